// Round 1
// baseline (815.889 us; speedup 1.0000x reference)
//
#include <hip/hip_runtime.h>
#include <hip/hip_bf16.h>
#include <cstdint>
#include <cstddef>

#define B_    1024
#define L_    200
#define DIN_  256
#define DOUT_ 256
#define K_    8

// ---------------- dtype helpers: MT = float (preferred) or unsigned short (bf16 bits, ws fallback)
__device__ __forceinline__ float bf2f(unsigned short u) {
  union { unsigned int i; float f; } w; w.i = ((unsigned int)u) << 16; return w.f;
}
__device__ __forceinline__ unsigned short f2bf(float f) {
  union { float f; unsigned int i; } w; w.f = f;
  unsigned int x = w.i;
  return (unsigned short)((x + 0x7fffu + ((x >> 16) & 1u)) >> 16);
}
__device__ __forceinline__ float ld1(const float* p) { return *p; }
__device__ __forceinline__ float ld1(const unsigned short* p) { return bf2f(*p); }
__device__ __forceinline__ void load4f(const float* p, float4& v) { v = *(const float4*)p; }
__device__ __forceinline__ void load4f(const unsigned short* p, float4& v) {
  ushort4 u = *(const ushort4*)p;
  v.x = bf2f(u.x); v.y = bf2f(u.y); v.z = bf2f(u.z); v.w = bf2f(u.w);
}
__device__ __forceinline__ void stor4f(float4 v, float* p) { *(float4*)p = v; }
__device__ __forceinline__ void stor4f(float4 v, unsigned short* p) {
  ushort4 u; u.x = f2bf(v.x); u.y = f2bf(v.y); u.z = f2bf(v.z); u.w = f2bf(v.w);
  *(ushort4*)p = u;
}

// ---------------- kernel 1: mapped[b,l,:] = behavior[b,l,:] @ W   (fp32 VALU GEMM)
// M=204800, K=256, N=256. 128x128 tile, BK=16, 8x8 micro-tile per thread.
template <typename MT>
__global__ __launch_bounds__(256)
void gemm_mapped(const float* __restrict__ A, const float* __restrict__ W, MT* __restrict__ C)
{
  const int tile_m = blockIdx.x;   // 1600
  const int tile_n = blockIdx.y;   // 2
  const int t = threadIdx.x;
  __shared__ float As[16][132];    // A stored transposed [k][m], pad 132 to break bank strides
  __shared__ float Bs[16][132];
  const int tm = t >> 4, tn = t & 15;
  const int m0 = tile_m * 128;
  const int n0 = tile_n * 128;

  float acc[8][8];
  #pragma unroll
  for (int i = 0; i < 8; ++i)
    #pragma unroll
    for (int j = 0; j < 8; ++j) acc[i][j] = 0.f;

  const int ar = t >> 1;           // 0..127 : A row within tile
  const int ks = (t & 1) * 8;      // k sub-offset
  const int br = t >> 4;           // 0..15  : W row within chunk
  const int cb = (t & 15) * 8;     // col offset
  const float* Ab = A + (size_t)m0 * DIN_;

  for (int k0 = 0; k0 < DIN_; k0 += 16) {
    float4 a0 = *(const float4*)(Ab + (size_t)ar * DIN_ + k0 + ks);
    float4 a1 = *(const float4*)(Ab + (size_t)ar * DIN_ + k0 + ks + 4);
    float4 b0 = *(const float4*)(W + (size_t)(k0 + br) * DOUT_ + n0 + cb);
    float4 b1 = *(const float4*)(W + (size_t)(k0 + br) * DOUT_ + n0 + cb + 4);
    As[ks+0][ar] = a0.x; As[ks+1][ar] = a0.y; As[ks+2][ar] = a0.z; As[ks+3][ar] = a0.w;
    As[ks+4][ar] = a1.x; As[ks+5][ar] = a1.y; As[ks+6][ar] = a1.z; As[ks+7][ar] = a1.w;
    *(float4*)&Bs[br][cb]     = b0;
    *(float4*)&Bs[br][cb + 4] = b1;
    __syncthreads();
    #pragma unroll
    for (int kk = 0; kk < 16; ++kk) {
      float4 a0q = *(const float4*)&As[kk][tm*8];
      float4 a1q = *(const float4*)&As[kk][tm*8+4];
      float4 b0q = *(const float4*)&Bs[kk][tn*8];
      float4 b1q = *(const float4*)&Bs[kk][tn*8+4];
      float av[8] = {a0q.x,a0q.y,a0q.z,a0q.w,a1q.x,a1q.y,a1q.z,a1q.w};
      float bv[8] = {b0q.x,b0q.y,b0q.z,b0q.w,b1q.x,b1q.y,b1q.z,b1q.w};
      #pragma unroll
      for (int i = 0; i < 8; ++i)
        #pragma unroll
        for (int j = 0; j < 8; ++j) acc[i][j] += av[i] * bv[j];
    }
    __syncthreads();
  }
  #pragma unroll
  for (int i = 0; i < 8; ++i) {
    int row = m0 + tm*8 + i;
    MT* cp = C + (size_t)row * DOUT_ + n0 + tn*8;
    stor4f(make_float4(acc[i][0], acc[i][1], acc[i][2], acc[i][3]), cp);
    stor4f(make_float4(acc[i][4], acc[i][5], acc[i][6], acc[i][7]), cp + 4);
  }
}

// ---------------- kernel 2: per-b fused masked-softmax + Z + squash
// block = one b, 256 threads, thread t = output channel o.
template <typename MT>
__global__ __launch_bounds__(256)
void z_kernel(const MT* __restrict__ mapped, const float* __restrict__ logits,
              const int* __restrict__ seq_len, float* __restrict__ caps)
{
  const int b = blockIdx.x;
  const int t = threadIdx.x;
  const int len = seq_len[b];          // 1..200
  __shared__ float w[K_][L_];
  __shared__ float red[256];

  for (int k = 0; k < K_; ++k) {
    float v = (t < len) ? logits[k*L_ + t] : -3.4028235e38f;
    red[t] = v; __syncthreads();
    #pragma unroll
    for (int s = 128; s > 0; s >>= 1) {
      if (t < s) red[t] = fmaxf(red[t], red[t+s]);
      __syncthreads();
    }
    float mx = red[0]; __syncthreads();
    float e = (t < len) ? __expf(v - mx) : 0.f;
    red[t] = e; __syncthreads();
    #pragma unroll
    for (int s = 128; s > 0; s >>= 1) {
      if (t < s) red[t] += red[t+s];
      __syncthreads();
    }
    float sum = red[0]; __syncthreads();
    if (t < L_) w[k][t] = e / sum;     // exactly 0 for t >= len (matches NEG_INF softmax)
  }
  __syncthreads();

  float acc[K_];
  #pragma unroll
  for (int k = 0; k < K_; ++k) acc[k] = 0.f;
  const MT* mp = mapped + (size_t)b * L_ * DOUT_ + t;
  int l = 0;
  for (; l + 2 <= len; l += 2) {       // weight==0 beyond len -> skip those rows entirely
    float m0 = ld1(mp);
    float m1 = ld1(mp + DOUT_);
    #pragma unroll
    for (int k = 0; k < K_; ++k) {
      float2 wv = *(const float2*)&w[k][l];
      acc[k] += wv.x * m0 + wv.y * m1;
    }
    mp += 2 * DOUT_;
  }
  if (l < len) {
    float m0 = ld1(mp);
    #pragma unroll
    for (int k = 0; k < K_; ++k) acc[k] += w[k][l] * m0;
  }

  #pragma unroll
  for (int k = 0; k < K_; ++k) {
    red[t] = acc[k] * acc[k]; __syncthreads();
    #pragma unroll
    for (int s = 128; s > 0; s >>= 1) {
      if (t < s) red[t] += red[t+s];
      __syncthreads();
    }
    float sq = red[0]; __syncthreads();
    float scale = sq / ((1.f + sq) * sqrtf(sq + 1e-8f));
    caps[((size_t)b * K_ + k) * DOUT_ + t] = scale * acc[k];
  }
}

// ---------------- kernel 3: delta partials. grid (7 l-tiles, 64 b-chunks of 16).
// Deterministic: each block writes its own partial [K][32], reduce kernel sums over b-chunks.
#define LTILE 32
#define DSTR  260

template <typename MT>
__global__ __launch_bounds__(256)
void delta_kernel(const MT* __restrict__ mapped, const float* __restrict__ caps,
                  float* __restrict__ partials)
{
  const int lt = blockIdx.x;   // 0..6
  const int bc = blockIdx.y;   // 0..63
  const int t  = threadIdx.x;
  __shared__ float capS[K_ * DSTR];      // capsule[k][o]
  __shared__ float mtS[LTILE * DSTR];    // mapped l-tile [l][o]

  const int ox   = t & 15;     // 16 lanes span o contiguously (bank-friendly)
  const int grp  = t >> 4;     // 16 groups: (kp, lgrp)
  const int kp   = grp & 1;    // k in {kp*4 .. kp*4+3}
  const int lgrp = grp >> 1;   // l in {lgrp*4 .. lgrp*4+3}
  const int l0   = lt * LTILE;

  float acc[4][4];
  #pragma unroll
  for (int i = 0; i < 4; ++i)
    #pragma unroll
    for (int j = 0; j < 4; ++j) acc[i][j] = 0.f;

  for (int bi = 0; bi < 16; ++bi) {
    const int b = bc * 16 + bi;
    const float* cp = caps + (size_t)b * (K_ * DOUT_);
    #pragma unroll
    for (int r = 0; r < 2; ++r) {
      int e = r * 1024 + t * 4;
      int k = e >> 8, o = e & 255;
      *(float4*)&capS[k * DSTR + o] = *(const float4*)&cp[e];
    }
    const MT* mpb = mapped + (size_t)b * (L_ * DOUT_);
    #pragma unroll
    for (int r = 0; r < 8; ++r) {
      int e = r * 1024 + t * 4;
      int ll = e >> 8, o = e & 255;
      int gl = l0 + ll;
      float4 v;
      if (gl < L_) load4f(mpb + (size_t)gl * DOUT_ + o, v);
      else         v = make_float4(0.f, 0.f, 0.f, 0.f);
      *(float4*)&mtS[ll * DSTR + o] = v;
    }
    __syncthreads();
    #pragma unroll
    for (int i = 0; i < 4; ++i) {
      const int o = ox * 4 + 64 * i;
      float4 c0 = *(const float4*)&capS[(kp*4+0) * DSTR + o];
      float4 c1 = *(const float4*)&capS[(kp*4+1) * DSTR + o];
      float4 c2 = *(const float4*)&capS[(kp*4+2) * DSTR + o];
      float4 c3 = *(const float4*)&capS[(kp*4+3) * DSTR + o];
      #pragma unroll
      for (int jl = 0; jl < 4; ++jl) {
        float4 m = *(const float4*)&mtS[(lgrp*4+jl) * DSTR + o];
        acc[0][jl] += c0.x*m.x + c0.y*m.y + c0.z*m.z + c0.w*m.w;
        acc[1][jl] += c1.x*m.x + c1.y*m.y + c1.z*m.z + c1.w*m.w;
        acc[2][jl] += c2.x*m.x + c2.y*m.y + c2.z*m.z + c2.w*m.w;
        acc[3][jl] += c3.x*m.x + c3.y*m.y + c3.z*m.z + c3.w*m.w;
      }
    }
    __syncthreads();
  }
  // reduce across the 16 lanes (ox) sharing each (k,l)
  #pragma unroll
  for (int ki = 0; ki < 4; ++ki)
    #pragma unroll
    for (int jl = 0; jl < 4; ++jl) {
      float v = acc[ki][jl];
      v += __shfl_xor(v, 1, 64);
      v += __shfl_xor(v, 2, 64);
      v += __shfl_xor(v, 4, 64);
      v += __shfl_xor(v, 8, 64);
      if (ox == 0) {
        int k = kp * 4 + ki;
        int gl = l0 + lgrp * 4 + jl;
        if (gl < L_) partials[((size_t)bc * K_ + k) * L_ + gl] = v;
      }
    }
}

// ---------------- small kernels
__global__ __launch_bounds__(256)
void init_logits(const float* __restrict__ rlog, float* __restrict__ logits)
{
  int i = blockIdx.x * 256 + threadIdx.x;
  if (i < K_ * L_) logits[i] = rlog[i];
}

__global__ __launch_bounds__(256)
void reduce_kernel(const float* __restrict__ partials, float* __restrict__ logits)
{
  int i = blockIdx.x * 256 + threadIdx.x;
  if (i < K_ * L_) {
    float s = 0.f;
    #pragma unroll 4
    for (int bc = 0; bc < 64; ++bc) s += partials[bc * (K_ * L_) + i];
    logits[i] += s;
  }
}

// ---------------- pipeline
template <typename MT>
static void run_pipeline(MT* mapped, const float* behav, const float* W, const int* slen,
                         float* logitsW, float* partials, float* caps, hipStream_t stream)
{
  gemm_mapped<MT><<<dim3(1600, 2), 256, 0, stream>>>(behav, W, mapped);
  for (int it = 0; it < 3; ++it) {
    z_kernel<MT><<<dim3(B_), 256, 0, stream>>>(mapped, logitsW, slen, caps);
    if (it < 2) {   // delta after last iteration is dead code in the reference
      delta_kernel<MT><<<dim3(7, 64), 256, 0, stream>>>(mapped, caps, partials);
      reduce_kernel<<<dim3(7), 256, 0, stream>>>(partials, logitsW);
    }
  }
}

extern "C" void kernel_launch(void* const* d_in, const int* in_sizes, int n_in,
                              void* d_out, int out_size, void* d_ws, size_t ws_size,
                              hipStream_t stream)
{
  const float* behav = (const float*)d_in[0];
  const int*   slen  = (const int*)d_in[1];
  const float* rlog  = (const float*)d_in[2];
  const float* W     = (const float*)d_in[3];
  float* caps = (float*)d_out;

  char* ws = (char*)d_ws;
  float* logitsW  = (float*)ws;                 // 6400 B
  float* partials = (float*)(ws + 8192);        // 64*8*200*4 = 409600 B
  void*  mapped   = (void*)(ws + (1 << 20));    // 200 MiB fp32 (or 100 MiB bf16 fallback)

  const size_t mapBytesF32 = (size_t)B_ * L_ * DOUT_ * sizeof(float);
  const bool f32path = ws_size >= ((size_t)(1 << 20) + mapBytesF32);

  init_logits<<<dim3(7), 256, 0, stream>>>(rlog, logitsW);
  if (f32path)
    run_pipeline<float>((float*)mapped, behav, W, slen, logitsW, partials, caps, stream);
  else
    run_pipeline<unsigned short>((unsigned short*)mapped, behav, W, slen, logitsW, partials, caps, stream);
}